// Round 1
// baseline (8187.320 us; speedup 1.0000x reference)
//
#include <hip/hip_runtime.h>
#include <stdint.h>

#define TT 512
#define BSZ 128
#define NN 512   // ecnum == ca1num == ca3num

// ---------- helpers ----------
__device__ __forceinline__ float sigmoidf_(float x) {
    return 1.0f / (1.0f + __expf(-x));
}

__device__ __forceinline__ uint32_t bf16_rne(uint32_t b) {
    // round-to-nearest-even fp32 -> bf16 (as low 16 bits)
    return (b + 0x7FFFu + ((b >> 16) & 1u)) >> 16;
}

// ---------- prep 1: ca3drive = ca3 @ wca3ca1  (T x N) ----------
// centers = linspace(-0.1T, 1.1T, N)[ca3order]; ca3[t,c] = exp(-(centers[c]-t)^2/(2*25))
__global__ void prep_ca3drive(const float* __restrict__ wca3ca1,
                              const int* __restrict__ ca3order,
                              float* __restrict__ drive) {
    __shared__ float ca3_sh[NN];
    const int t = blockIdx.x;
    const int j = threadIdx.x;
    // compute ca3[t, j] (j is the ca3 index here)
    int ord = ca3order[j];
    float center = -51.2f + (614.4f / 511.0f) * (float)ord;
    float d = center - (float)t;
    ca3_sh[j] = __expf(-(d * d) * 0.02f);   // /(SIGMA^2)/2 = *0.02
    __syncthreads();
    float acc = 0.0f;
#pragma unroll 8
    for (int c = 0; c < NN; ++c) {
        acc = fmaf(ca3_sh[c], wca3ca1[c * NN + j], acc);
    }
    drive[t * NN + j] = acc;
}

// ---------- prep 2: pack fp32 weight matrix (N x N, row-major k x j) ----------
// wp[q*NN + j] = uint2{ pack(w[4q][j], w[4q+1][j]), pack(w[4q+2][j], w[4q+3][j]) }
// packed word u: low bf16 = even k (float bits = u<<16), high bf16 = odd k (u & 0xFFFF0000)
__global__ void prep_pack(const float* __restrict__ w, uint2* __restrict__ wp) {
    int idx = blockIdx.x * blockDim.x + threadIdx.x;   // 0 .. 128*512-1
    int j = idx & (NN - 1);
    int q = idx >> 9;
    const float* col = w + j;
    uint32_t r0 = bf16_rne(__float_as_uint(col[(4 * q + 0) * NN]));
    uint32_t r1 = bf16_rne(__float_as_uint(col[(4 * q + 1) * NN]));
    uint32_t r2 = bf16_rne(__float_as_uint(col[(4 * q + 2) * NN]));
    uint32_t r3 = bf16_rne(__float_as_uint(col[(4 * q + 3) * NN]));
    uint2 o;
    o.x = (r0 & 0xFFFFu) | (r1 << 16);
    o.y = (r2 & 0xFFFFu) | (r3 << 16);
    wp[idx] = o;
}

// ---------- main recurrent kernel: one workgroup per batch row ----------
__global__ __launch_bounds__(512) void rnn_main(
    const float* __restrict__ ec3input,   // (BSZ, TT, NN)
    const float* __restrict__ ec3_last,   // (BSZ, NN)
    const float* __restrict__ ec5_last,   // (BSZ, NN)
    const float* __restrict__ ca1bias,    // (NN)
    const uint2* __restrict__ W1p,        // packed wec3ca1
    const uint2* __restrict__ W2p,        // packed wca1ec5
    const float* __restrict__ wca1act,    // (NN, 2)
    const float* __restrict__ actbias,    // (2)
    const int*   __restrict__ mask,       // (BSZ, TT, NN) as int32 0/1
    const float* __restrict__ drive_all,  // (TT, NN) from prep
    float* __restrict__ out)
{
    __shared__ __align__(16) float ec3_sh[NN];
    __shared__ __align__(16) float ca1_sh[NN];
    __shared__ float act_part[16];  // 8 waves x 2

    const int b = blockIdx.x;
    const int j = threadIdx.x;

    float ec3 = ec3_last[b * NN + j];
    float ec5 = ec5_last[b * NN + j];
    const float bias = ca1bias[j];
    const float wa0 = wca1act[2 * j + 0];
    const float wa1 = wca1act[2 * j + 1];
    const float ab = (j < 2) ? actbias[j] : 0.0f;

    ec3_sh[j] = ec3;
    __syncthreads();

    const float* xin_b  = ec3input + (size_t)b * TT * NN;
    const int*   mask_b = mask     + (size_t)b * TT * NN;

    // output regions (floats), in reference return order
    float* out_act = out;                                  // 128*512*2
    float* out_e3h = out + (size_t)131072;                 // 128*512*512
    float* out_e5h = out_e3h + (size_t)33554432;
    float* out_c1h = out_e5h + (size_t)33554432;
    float* out_e3  = out_c1h + (size_t)33554432;           // 128*512
    float* out_e5  = out_e3 + (size_t)65536;
    float* out_c1  = out_e5 + (size_t)65536;

    float ca1 = 0.0f;

    for (int t = 0; t < TT; ++t) {
        // ---- matvec1: s1 = sum_k ec3_sh[k] * W1[k][j] ----
        float s1 = 0.0f;
#pragma unroll 4
        for (int q = 0; q < 128; ++q) {
            uint2 u = W1p[q * NN + j];
            float4 a = *(const float4*)&ec3_sh[4 * q];
            s1 = fmaf(a.x, __uint_as_float(u.x << 16), s1);
            s1 = fmaf(a.y, __uint_as_float(u.x & 0xFFFF0000u), s1);
            s1 = fmaf(a.z, __uint_as_float(u.y << 16), s1);
            s1 = fmaf(a.w, __uint_as_float(u.y & 0xFFFF0000u), s1);
        }
        float drive = drive_all[t * NN + j];
        ca1 = drive * (1.0f + sigmoidf_(s1)) - bias;
        ca1 = fminf(fmaxf(ca1, 0.0f), 1.0f);
        ca1_sh[j] = ca1;

        // act partials: reduce ca1*wa over the wave
        float p0 = ca1 * wa0;
        float p1 = ca1 * wa1;
#pragma unroll
        for (int off = 32; off > 0; off >>= 1) {
            p0 += __shfl_down(p0, off, 64);
            p1 += __shfl_down(p1, off, 64);
        }
        if ((j & 63) == 0) {
            act_part[(j >> 6) * 2 + 0] = p0;
            act_part[(j >> 6) * 2 + 1] = p1;
        }
        __syncthreads();   // barrier A: ca1_sh + act_part visible

        // ---- matvec2: s2 = sum_k ca1_sh[k] * W2[k][j] ----
        float s2 = 0.0f;
#pragma unroll 4
        for (int q = 0; q < 128; ++q) {
            uint2 u = W2p[q * NN + j];
            float4 a = *(const float4*)&ca1_sh[4 * q];
            s2 = fmaf(a.x, __uint_as_float(u.x << 16), s2);
            s2 = fmaf(a.y, __uint_as_float(u.x & 0xFFFF0000u), s2);
            s2 = fmaf(a.z, __uint_as_float(u.y << 16), s2);
            s2 = fmaf(a.w, __uint_as_float(u.y & 0xFFFF0000u), s2);
        }
        // ec5 update: ec5 += 10*TS*s2 = s2; then squash
        ec5 = ec5 + s2;
        ec5 = 0.69f + 0.3f * sigmoidf_(4.0f * (ec5 - 0.3f));

        // ec3 update
        float x = xin_b[t * NN + j];
        int m = mask_b[t * NN + j];
        ec3 = ec5 * ec3 + 0.6f * (1.0f - ec3) * x;
        if (m) ec3 = 0.5f * ec3 + 0.3f;

        // ---- outputs ----
        size_t ho = ((size_t)b * TT + t) * NN + j;
        out_e3h[ho] = ec3;
        out_e5h[ho] = ec5;
        out_c1h[ho] = ca1;
        if (j < 2) {
            float s = 0.0f;
#pragma unroll
            for (int w = 0; w < 8; ++w) s += act_part[w * 2 + j];
            out_act[((size_t)b * TT + t) * 2 + j] = s + ab;
        }

        // publish new ec3 for next step's matvec1
        ec3_sh[j] = ec3;
        __syncthreads();   // barrier B
    }

    out_e3[b * NN + j] = ec3;
    out_e5[b * NN + j] = ec5;
    out_c1[b * NN + j] = ca1;
}

// ---------- launch ----------
extern "C" void kernel_launch(void* const* d_in, const int* in_sizes, int n_in,
                              void* d_out, int out_size, void* d_ws, size_t ws_size,
                              hipStream_t stream) {
    const float* ec3input = (const float*)d_in[0];
    const float* ec3_last = (const float*)d_in[1];
    const float* ec5_last = (const float*)d_in[2];
    /* d_in[3] ca1_last: unused by the recurrence */
    const float* ca1bias  = (const float*)d_in[4];
    const float* wca3ca1  = (const float*)d_in[5];
    const float* wec3ca1  = (const float*)d_in[6];
    const float* wca1ec5  = (const float*)d_in[7];
    const float* wca1act  = (const float*)d_in[8];
    const float* actbias  = (const float*)d_in[9];
    const int*   mask     = (const int*)d_in[10];
    const int*   ca3order = (const int*)d_in[11];
    float* out = (float*)d_out;

    char* ws = (char*)d_ws;
    float* drive = (float*)ws;                                // 512*512 f32 = 1 MB
    uint2* W1p = (uint2*)(ws + (1 << 20));                    // 128*512 uint2 = 512 KB
    uint2* W2p = (uint2*)(ws + (1 << 20) + (1 << 19));        // 512 KB

    hipLaunchKernelGGL(prep_ca3drive, dim3(TT), dim3(NN), 0, stream,
                       wca3ca1, ca3order, drive);
    hipLaunchKernelGGL(prep_pack, dim3(256), dim3(256), 0, stream, wec3ca1, W1p);
    hipLaunchKernelGGL(prep_pack, dim3(256), dim3(256), 0, stream, wca1ec5, W2p);
    hipLaunchKernelGGL(rnn_main, dim3(BSZ), dim3(NN), 0, stream,
                       ec3input, ec3_last, ec5_last, ca1bias,
                       W1p, W2p, wca1act, actbias, mask, drive, out);
}

// Round 2
// 5351.197 us; speedup vs baseline: 1.5300x; 1.5300x over previous
//
#include <hip/hip_runtime.h>
#include <stdint.h>

#define TT 512
#define BSZ 128
#define NN 512
#define USE_FDOT2 1

typedef _Float16 h2 __attribute__((ext_vector_type(2)));
typedef _Float16 h8 __attribute__((ext_vector_type(8)));

__device__ __forceinline__ float sigmoidf_(float x) {
    return 1.0f / (1.0f + __expf(-x));
}

#define H2P(v, i) __builtin_shufflevector((v), (v), 2 * (i), 2 * (i) + 1)

#if USE_FDOT2
#define DOT8(acc, w, a)                                                   \
    do {                                                                  \
        acc = __builtin_amdgcn_fdot2(H2P(w, 0), H2P(a, 0), acc, false);   \
        acc = __builtin_amdgcn_fdot2(H2P(w, 1), H2P(a, 1), acc, false);   \
        acc = __builtin_amdgcn_fdot2(H2P(w, 2), H2P(a, 2), acc, false);   \
        acc = __builtin_amdgcn_fdot2(H2P(w, 3), H2P(a, 3), acc, false);   \
    } while (0)
#else
#define DOT8(acc, w, a)                                                   \
    do {                                                                  \
        _Pragma("unroll")                                                 \
        for (int _i = 0; _i < 8; ++_i)                                    \
            acc = fmaf((float)(w)[_i], (float)(a)[_i], acc);              \
    } while (0)
#endif

// ---------- prep 1: ca3drive = ca3 @ wca3ca1  (T x N), fp32 ----------
__global__ void prep_ca3drive(const float* __restrict__ wca3ca1,
                              const int* __restrict__ ca3order,
                              float* __restrict__ drive) {
    __shared__ float ca3_sh[NN];
    const int t = blockIdx.x;
    const int j = threadIdx.x;
    int ord = ca3order[j];
    float center = -51.2f + (614.4f / 511.0f) * (float)ord;
    float d = center - (float)t;
    ca3_sh[j] = __expf(-(d * d) * 0.02f);
    __syncthreads();
    float acc = 0.0f;
#pragma unroll 8
    for (int c = 0; c < NN; ++c) {
        acc = fmaf(ca3_sh[c], wca3ca1[c * NN + j], acc);
    }
    drive[t * NN + j] = acc;
}

// ---------- prep 2: pack fp32 (N x N, [k][j]) -> f16 h8 tiles ----------
// wp[qp*NN + j] = f16 of w[8qp + i][j], i=0..7
__global__ void prep_pack_f16(const float* __restrict__ w, h8* __restrict__ wp) {
    int idx = blockIdx.x * blockDim.x + threadIdx.x;   // 0 .. 64*512-1
    int j = idx & (NN - 1);
    int qp = idx >> 9;
    h8 o;
#pragma unroll
    for (int i = 0; i < 8; ++i) {
        o[i] = (_Float16)w[(8 * qp + i) * NN + j];
    }
    wp[idx] = o;
}

// ---------- main: 2 rows per WG, 1024 threads, in-block K-split ----------
__global__ __launch_bounds__(1024, 4) void rnn_main(
    const float* __restrict__ ec3input,   // (BSZ, TT, NN)
    const float* __restrict__ ec3_last,
    const float* __restrict__ ec5_last,
    const float* __restrict__ ca1bias,
    const h8*    __restrict__ W1p,        // f16-packed wec3ca1 [qp][j]
    const h8*    __restrict__ W2p,        // f16-packed wca1ec5
    const float* __restrict__ wca1act,    // (NN, 2)
    const float* __restrict__ actbias,    // (2)
    const int*   __restrict__ mask,       // (BSZ, TT, NN) int32
    const float* __restrict__ drive_all,  // (TT, NN)
    float* __restrict__ out)
{
    __shared__ __align__(16) _Float16 ec3h[2][NN];   // activations, f16
    __shared__ __align__(16) _Float16 ca1h[2][NN];
    __shared__ float part[2][2][NN];                 // [khalf][row][j]
    __shared__ float act_part[2][8][2];              // [row][wave][c]

    const int tid = threadIdx.x;
    const int h  = tid >> 9;      // matvec role: K-half
    const int jm = tid & (NN - 1);// matvec role: output index
    const int r  = h;             // pointwise role: row within pair
    const int jp = jm;            // pointwise role: element index

    const int b0 = 2 * blockIdx.x;
    const int br = b0 + r;

    float ec3 = ec3_last[br * NN + jp];
    float ec5 = ec5_last[br * NN + jp];
    float ca1 = 0.0f;
    const float bias = ca1bias[jp];
    const float wa0 = wca1act[2 * jp + 0];
    const float wa1 = wca1act[2 * jp + 1];

    ec3h[r][jp] = (_Float16)ec3;
    __syncthreads();

    const float* xin_r  = ec3input + (size_t)br * TT * NN;
    const int*   mask_r = mask     + (size_t)br * TT * NN;

    // output regions (floats), reference return order
    float* out_act = out;                                  // 128*512*2
    float* out_e3h = out + (size_t)131072;
    float* out_e5h = out_e3h + (size_t)33554432;
    float* out_c1h = out_e5h + (size_t)33554432;
    float* out_e3  = out_c1h + (size_t)33554432;
    float* out_e5  = out_e3 + (size_t)65536;
    float* out_c1  = out_e5 + (size_t)65536;

    const int qp0 = 32 * h;

    for (int t = 0; t < TT; ++t) {
        // ---- matvec1 partial over own K-half, both rows ----
        {
            float s0 = 0.0f, s1 = 0.0f;
#pragma unroll 4
            for (int qp = qp0; qp < qp0 + 32; ++qp) {
                h8 w  = W1p[qp * NN + jm];
                h8 a0 = *(const h8*)&ec3h[0][8 * qp];
                h8 a1 = *(const h8*)&ec3h[1][8 * qp];
                DOT8(s0, w, a0);
                DOT8(s1, w, a1);
            }
            part[h][0][jm] = s0;
            part[h][1][jm] = s1;
        }
        __syncthreads();   // B1: partials1 ready

        // ---- pointwise1: ca1 ----
        {
            float s1t = part[0][r][jp] + part[1][r][jp];
            float dr = drive_all[t * NN + jp];
            ca1 = dr * (1.0f + sigmoidf_(s1t)) - bias;
            ca1 = fminf(fmaxf(ca1, 0.0f), 1.0f);
            ca1h[r][jp] = (_Float16)ca1;
            size_t ho = ((size_t)br * TT + t) * NN + jp;
            out_c1h[ho] = ca1;
            float p0 = ca1 * wa0;
            float p1 = ca1 * wa1;
#pragma unroll
            for (int off = 32; off > 0; off >>= 1) {
                p0 += __shfl_down(p0, off, 64);
                p1 += __shfl_down(p1, off, 64);
            }
            if ((tid & 63) == 0) {
                act_part[r][(tid >> 6) & 7][0] = p0;
                act_part[r][(tid >> 6) & 7][1] = p1;
            }
        }
        __syncthreads();   // B2: ca1h + act_part ready; part[] free

        // ---- matvec2 partial over own K-half, both rows ----
        {
            float s0 = 0.0f, s1 = 0.0f;
#pragma unroll 4
            for (int qp = qp0; qp < qp0 + 32; ++qp) {
                h8 w  = W2p[qp * NN + jm];
                h8 a0 = *(const h8*)&ca1h[0][8 * qp];
                h8 a1 = *(const h8*)&ca1h[1][8 * qp];
                DOT8(s0, w, a0);
                DOT8(s1, w, a1);
            }
            part[h][0][jm] = s0;
            part[h][1][jm] = s1;
        }
        __syncthreads();   // B3: partials2 ready

        // ---- pointwise2: ec5, ec3, history, act ----
        {
            float s2t = part[0][r][jp] + part[1][r][jp];
            ec5 = ec5 + s2t;   // 10*TS = 1.0
            ec5 = 0.69f + 0.3f * sigmoidf_(4.0f * (ec5 - 0.3f));
            float x = xin_r[t * NN + jp];
            int m = mask_r[t * NN + jp];
            ec3 = ec5 * ec3 + 0.6f * (1.0f - ec3) * x;
            if (m) ec3 = 0.5f * ec3 + 0.3f;
            size_t ho = ((size_t)br * TT + t) * NN + jp;
            out_e3h[ho] = ec3;
            out_e5h[ho] = ec5;
            ec3h[r][jp] = (_Float16)ec3;
            if (tid < 4) {
                int rr = tid >> 1, cc = tid & 1;
                float s = actbias[cc];
#pragma unroll
                for (int w = 0; w < 8; ++w) s += act_part[rr][w][cc];
                out_act[((size_t)(b0 + rr) * TT + t) * 2 + cc] = s;
            }
        }
        __syncthreads();   // B4: ec3h ready for next step; part/act free
    }

    out_e3[br * NN + jp] = ec3;
    out_e5[br * NN + jp] = ec5;
    out_c1[br * NN + jp] = ca1;
}

// ---------- launch ----------
extern "C" void kernel_launch(void* const* d_in, const int* in_sizes, int n_in,
                              void* d_out, int out_size, void* d_ws, size_t ws_size,
                              hipStream_t stream) {
    const float* ec3input = (const float*)d_in[0];
    const float* ec3_last = (const float*)d_in[1];
    const float* ec5_last = (const float*)d_in[2];
    /* d_in[3] ca1_last unused */
    const float* ca1bias  = (const float*)d_in[4];
    const float* wca3ca1  = (const float*)d_in[5];
    const float* wec3ca1  = (const float*)d_in[6];
    const float* wca1ec5  = (const float*)d_in[7];
    const float* wca1act  = (const float*)d_in[8];
    const float* actbias  = (const float*)d_in[9];
    const int*   mask     = (const int*)d_in[10];
    const int*   ca3order = (const int*)d_in[11];
    float* out = (float*)d_out;

    char* ws = (char*)d_ws;
    float* drive = (float*)ws;                         // 1 MB
    h8* W1p = (h8*)(ws + (1 << 20));                   // 512 KB
    h8* W2p = (h8*)(ws + (1 << 20) + (1 << 19));       // 512 KB

    hipLaunchKernelGGL(prep_ca3drive, dim3(TT), dim3(NN), 0, stream,
                       wca3ca1, ca3order, drive);
    hipLaunchKernelGGL(prep_pack_f16, dim3(128), dim3(256), 0, stream, wec3ca1, W1p);
    hipLaunchKernelGGL(prep_pack_f16, dim3(128), dim3(256), 0, stream, wca1ec5, W2p);
    hipLaunchKernelGGL(rnn_main, dim3(BSZ / 2), dim3(1024), 0, stream,
                       ec3input, ec3_last, ec5_last, ca1bias,
                       W1p, W2p, wca1act, actbias, mask, drive, out);
}